// Round 1
// baseline (21933.714 us; speedup 1.0000x reference)
//
#include <hip/hip_runtime.h>
#include <math.h>

#define DIMN 20
#define DD 21
#define NN 2048
#define MCN 32
#define UNITS 128
#define NLAYERS 3
#define SIGC 0.2f
#define MUC 0.05f
#define RC 0.05f
#define DELTAC 0.01f

#define TM 16
#define SB 132
#define PTOT (NN + MCN*NN + NN)
#define NBLK (PTOT/TM)

// ws layout in floats
#define OFF_L 0
#define OFF_WT 512
#define OFF_FP1 (512 + 4*16384)
#define OFF_VAL1 (OFF_FP1 + NN*DD)
#define OFF_VAL2 (OFF_VAL1 + NN)
#define OFF_T12  (OFF_VAL2 + NN)

__global__ void chol_kernel(float* __restrict__ Lout)
{
    if (threadIdx.x == 0 && blockIdx.x == 0) {
        double Lc[DIMN][DIMN];
        for (int i = 0; i < DIMN; i++)
            for (int j = 0; j <= i; j++) {
                double s = 0.01 * (0.5 + (i == j ? 0.5 : 0.0));
                for (int t2 = 0; t2 < j; t2++) s -= Lc[i][t2] * Lc[j][t2];
                Lc[i][j] = (i == j) ? sqrt(s) : s / Lc[j][j];
            }
        for (int i = 0; i < DIMN; i++)
            for (int j = 0; j < DIMN; j++)
                Lout[i*DIMN + j] = (j <= i) ? (float)Lc[i][j] : 0.0f;
    }
}

__global__ void transpose_k(const float* __restrict__ wz, const float* __restrict__ wg,
                            const float* __restrict__ wr, const float* __restrict__ wh,
                            float* __restrict__ WT)
{
    int idx = blockIdx.x*256 + threadIdx.x;           // 0..65535
    int q = idx >> 14, r2 = idx & 16383, k = r2 >> 7, j = r2 & 127;
    const float* src = (q==0)? wz : (q==1)? wg : (q==2)? wr : wh;
    WT[(q<<14) + j*UNITS + k] = src[k*UNITS + j];
}

// out[pt][j0..j0+7] = tanh(b + x@U)   (first layer: no W term)
__device__ __forceinline__ void gate_x(const float* __restrict__ U, const float* __restrict__ bias,
    const float xt[TM][22], float* __restrict__ out, int pt, int j0)
{
    float acc[8];
    #pragma unroll
    for (int jj=0;jj<8;jj++) acc[jj] = bias[j0+jj];
    for (int k=0;k<DD;k++){
        float xv = xt[pt][k];
        const float* u = U + k*UNITS + j0;
        #pragma unroll
        for (int jj=0;jj<8;jj++) acc[jj] = fmaf(xv, u[jj], acc[jj]);
    }
    #pragma unroll
    for (int jj=0;jj<8;jj++) out[pt*SB + j0 + jj] = tanhf(acc[jj]);
}

// out = tanh(b + x@U + S@W)
__device__ __forceinline__ void gate_sw(const float* __restrict__ U, const float* __restrict__ W,
    const float* __restrict__ bias, const float xt[TM][22], const float* __restrict__ S,
    float* __restrict__ out, int pt, int j0)
{
    float acc[8];
    #pragma unroll
    for (int jj=0;jj<8;jj++) acc[jj] = bias[j0+jj];
    for (int k=0;k<DD;k++){
        float xv = xt[pt][k];
        const float* u = U + k*UNITS + j0;
        #pragma unroll
        for (int jj=0;jj<8;jj++) acc[jj] = fmaf(xv, u[jj], acc[jj]);
    }
    for (int k=0;k<UNITS;k++){
        float sv = S[pt*SB + k];
        const float* w = W + k*UNITS + j0;
        #pragma unroll
        for (int jj=0;jj<8;jj++) acc[jj] = fmaf(sv, w[jj], acc[jj]);
    }
    #pragma unroll
    for (int jj=0;jj<8;jj++) out[pt*SB + j0 + jj] = tanhf(acc[jj]);
}

// out[pt][j0..] = sum_j P[pt][j] * WT[j][j0..]
__device__ __forceinline__ void wtmm1(const float* __restrict__ WTq, const float* __restrict__ P,
    float* __restrict__ out, int pt, int j0)
{
    float acc[8];
    #pragma unroll
    for (int jj=0;jj<8;jj++) acc[jj] = 0.f;
    for (int j=0;j<UNITS;j++){
        float pv = P[pt*SB + j];
        const float* w = WTq + j*UNITS + j0;
        #pragma unroll
        for (int jj=0;jj<8;jj++) acc[jj] = fmaf(pv, w[jj], acc[jj]);
    }
    #pragma unroll
    for (int jj=0;jj<8;jj++) out[pt*SB + j0 + jj] = acc[jj];
}

// out += Z@WTz + G@WTg + R@WTr
__device__ __forceinline__ void wtmm3(const float* __restrict__ WTz, const float* __restrict__ WTg,
    const float* __restrict__ WTr, const float* __restrict__ Z, const float* __restrict__ G,
    const float* __restrict__ Rb, float* __restrict__ out, int pt, int j0)
{
    float acc[8];
    #pragma unroll
    for (int jj=0;jj<8;jj++) acc[jj] = out[pt*SB + j0 + jj];
    for (int j=0;j<UNITS;j++){
        float zv = Z[pt*SB + j], gv = G[pt*SB + j], rv = Rb[pt*SB + j];
        const float* a = WTz + j*UNITS + j0;
        const float* b = WTg + j*UNITS + j0;
        const float* c = WTr + j*UNITS + j0;
        #pragma unroll
        for (int jj=0;jj<8;jj++){
            acc[jj] = fmaf(zv, a[jj], acc[jj]);
            acc[jj] = fmaf(gv, b[jj], acc[jj]);
            acc[jj] = fmaf(rv, c[jj], acc[jj]);
        }
    }
    #pragma unroll
    for (int jj=0;jj<8;jj++) out[pt*SB + j0 + jj] = acc[jj];
}

// dxt[p][i] += sum_j P[p][j] * U[i][j]   (i covers 0..20 via i and i+16 for i<5)
__device__ __forceinline__ void dxacc1(const float* __restrict__ U, const float* __restrict__ P,
    float dxt[TM][22], int t)
{
    int p2 = t >> 4, i = t & 15;
    const float* r0 = U + i*UNITS;
    const float* r1 = U + ((i < 5) ? (i+16) : i)*UNITS;
    float a0 = 0.f, a1 = 0.f;
    for (int j=0;j<UNITS;j++){
        float pv = P[p2*SB + j];
        a0 = fmaf(pv, r0[j], a0);
        a1 = fmaf(pv, r1[j], a1);
    }
    dxt[p2][i] += a0;
    if (i < 5) dxt[p2][i+16] += a1;
}

__global__ __launch_bounds__(256) void dgm_main(
    const float* __restrict__ inputs, const float* __restrict__ eps,
    const float* __restrict__ w1, const float* __restrict__ b1,
    const float* __restrict__ uz, const float* __restrict__ wz, const float* __restrict__ bz,
    const float* __restrict__ ug, const float* __restrict__ wg, const float* __restrict__ bg,
    const float* __restrict__ ur, const float* __restrict__ wr, const float* __restrict__ br,
    const float* __restrict__ uh, const float* __restrict__ wh, const float* __restrict__ bh,
    const float* __restrict__ wv, const float* __restrict__ bv,
    const float* __restrict__ Lm, const float* __restrict__ WT,
    float* __restrict__ fp1, float* __restrict__ val1, float* __restrict__ val2,
    float* __restrict__ t12acc)
{
    __shared__ float buf[7][TM*SB];
    __shared__ float xt[TM][22];
    __shared__ float Vt[TM][DIMN];
    __shared__ float dxt[TM][22];

    const int t  = threadIdx.x;
    const int pt = t >> 4;
    const int j0 = (t & 15) << 3;
    const int P0 = blockIdx.x * TM;
    const int type = (P0 < NN) ? 0 : (P0 < NN + MCN*NN) ? 1 : 2;

    // ---- build x tile (and violation tile for xplus) ----
    for (int e = t; e < TM*DD; e += 256){
        int pp = e / DD, k = e - pp*DD;
        int p  = P0 + pp;
        float xv;
        if (type == 0) xv = inputs[p*DD + k];
        else if (type == 2){ int n2 = p - (NN + MCN*NN); xv = inputs[(NN + n2)*DD + k]; }
        else {
            int q = p - NN; int m = q >> 11; int n = q & (NN-1);
            float x1v = inputs[n*DD + k];
            if (k == DIMN) xv = x1v;
            else {
                const float* ep = eps + (m*NN + n)*DIMN;
                float acc = x1v;
                for (int d2=0; d2<DIMN; d2++) acc = fmaf(ep[d2], Lm[k*DIMN + d2], acc);
                float v = acc * (SIGC * x1v);
                Vt[pp][k] = v;
                xv = x1v + v;
            }
        }
        xt[pp][k] = xv;
    }
    __syncthreads();

    float s0r[8], s1r[8], s2r[8];
    float* S  = buf[0]; float* DS = buf[1]; float* Z = buf[2]; float* G = buf[3];
    float* Rb = buf[4]; float* T  = buf[5]; float* H = buf[6];

    // ---- forward ----
    gate_x(w1, b1, xt, S, pt, j0);
    #pragma unroll
    for (int jj=0;jj<8;jj++) s0r[jj] = S[pt*SB + j0 + jj];
    __syncthreads();

    for (int L = 0; L < NLAYERS; L++){
        gate_sw(uz, wz, bz, xt, S, Z,  pt, j0);
        gate_sw(ug, wg, bg, xt, S, G,  pt, j0);
        gate_sw(ur, wr, br, xt, S, Rb, pt, j0);
        #pragma unroll
        for (int jj=0;jj<8;jj++){ int o = pt*SB + j0 + jj; T[o] = S[o]*Rb[o]; }
        __syncthreads();
        gate_sw(uh, wh, bh, xt, T, H, pt, j0);
        // s-update: all elementwise at own positions; S readers are past the sync above
        #pragma unroll
        for (int jj=0;jj<8;jj++){
            int o = pt*SB + j0 + jj;
            float sn = (1.f - G[o])*H[o] + Z[o]*S[o];
            S[o] = sn;
            if (L == 0) s1r[jj] = sn; else if (L == 1) s2r[jj] = sn;
        }
        __syncthreads();
    }

    // ---- value head (S holds s3) ----
    {
        float part = 0.f;
        #pragma unroll
        for (int jj=0;jj<8;jj++) part += S[pt*SB + j0 + jj] * wv[j0 + jj];
        Z[pt*16 + (t & 15)] = part;
        __syncthreads();
        if ((t & 15) == 0){
            float v = bv[0];
            for (int i2=0;i2<16;i2++) v += Z[pt*16 + i2];
            if (type == 0) val1[P0 + pt] = v;
            else if (type == 2) val2[P0 + pt - (NN + MCN*NN)] = v;
        }
        __syncthreads();
    }

    if (type == 2) return;

    // ---- backward (x1 and xplus tiles) ----
    #pragma unroll
    for (int jj=0;jj<8;jj++) DS[pt*SB + j0 + jj] = wv[j0 + jj];
    for (int e = t; e < TM*22; e += 256) ((float*)dxt)[e] = 0.f;
    __syncthreads();

    for (int L = NLAYERS-1; L >= 0; L--){
        const float* sr = (L == 2) ? s2r : (L == 1) ? s1r : s0r;
        #pragma unroll
        for (int jj=0;jj<8;jj++) S[pt*SB + j0 + jj] = sr[jj];
        __syncthreads();
        // recompute gates
        gate_sw(uz, wz, bz, xt, S, Z,  pt, j0);
        gate_sw(ug, wg, bg, xt, S, G,  pt, j0);
        gate_sw(ur, wr, br, xt, S, Rb, pt, j0);
        #pragma unroll
        for (int jj=0;jj<8;jj++){ int o = pt*SB + j0 + jj; T[o] = S[o]*Rb[o]; }
        __syncthreads();
        gate_sw(uh, wh, bh, xt, T, H, pt, j0);
        __syncthreads();          // all H matmuls done -> T reusable
        // e1: T = dh_pre, G = dg_pre
        #pragma unroll
        for (int jj=0;jj<8;jj++){
            int o = pt*SB + j0 + jj;
            float ds = DS[o], gv = G[o], hv = H[o];
            T[o] = ds*(1.f - gv)*(1.f - hv*hv);
            G[o] = -ds*hv*(1.f - gv*gv);
        }
        __syncthreads();
        wtmm1(WT + 3*16384, T, H, pt, j0);      // H = dsr
        dxacc1(uh, T, dxt, t);                  // dx += dh_pre @ Uh^T
        __syncthreads();                        // T free
        // e2: T = ds_new partial, Z = dz_pre, Rb = dr_pre
        #pragma unroll
        for (int jj=0;jj<8;jj++){
            int o = pt*SB + j0 + jj;
            float ds = DS[o], zv = Z[o], rv = Rb[o], dsr = H[o], sv = S[o];
            T[o]  = ds*zv + dsr*rv;
            Z[o]  = ds*sv*(1.f - zv*zv);
            Rb[o] = dsr*sv*(1.f - rv*rv);
        }
        __syncthreads();
        wtmm3(WT, WT + 16384, WT + 2*16384, Z, G, Rb, T, pt, j0);
        dxacc1(uz, Z,  dxt, t);
        dxacc1(ug, G,  dxt, t);
        dxacc1(ur, Rb, dxt, t);
        __syncthreads();
        { float* tmp = DS; DS = T; T = tmp; }
    }
    // first layer backward
    #pragma unroll
    for (int jj=0;jj<8;jj++){
        int o = pt*SB + j0 + jj;
        Z[o] = DS[o]*(1.f - s0r[jj]*s0r[jj]);
    }
    __syncthreads();
    dxacc1(w1, Z, dxt, t);
    __syncthreads();

    // ---- epilogue ----
    if (type == 0){
        for (int e = t; e < TM*DD; e += 256){
            int pp = e / DD, k = e - pp*DD;
            fp1[(P0 + pp)*DD + k] = dxt[pp][k];
        }
    } else {
        if (t < TM){
            float dot = 0.f;
            #pragma unroll
            for (int k=0;k<DIMN;k++) dot = fmaf(dxt[t][k], Vt[t][k], dot);
            int q = P0 + t - NN;
            int n = q & (NN-1);
            atomicAdd(t12acc + n, dot);
        }
    }
}

__global__ void finalize_k(const float* __restrict__ inputs, const float* __restrict__ eps,
    const float* __restrict__ Lm, const float* __restrict__ fp1, const float* __restrict__ val1,
    const float* __restrict__ val2, const float* __restrict__ t12acc, float* __restrict__ out)
{
    int n = blockIdx.x*256 + threadIdx.x;
    if (n >= NN) return;
    float fp[DD];
    for (int k=0;k<DD;k++) fp[k] = fp1[n*DD + k];
    // term1_1 = sum(drift * fprime)
    float t11 = fp[DIMN];
    for (int k=0;k<DIMN;k++) t11 = fmaf(MUC*inputs[n*DD + k], fp[k], t11);
    // sum over m of violation, reconstructed analytically
    float esum[DIMN];
    for (int d=0; d<DIMN; d++){
        float a = 0.f;
        for (int m=0; m<MCN; m++) a += eps[(m*NN + n)*DIMN + d];
        esum[d] = a;
    }
    float t12b = 0.f;
    for (int k=0;k<DIMN;k++){
        float loc = inputs[n*DD + k];
        float ssum = (float)MCN * loc;
        for (int d=0; d<DIMN; d++) ssum = fmaf(esum[d], Lm[k*DIMN + d], ssum);
        float vsum = ssum * (SIGC*loc);
        t12b = fmaf(fp[k], vsum, t12b);
    }
    float term12 = (t12acc[n] - t12b) * (1.0f/(DELTAC*(float)MCN));
    out[n] = t11 + 0.5f*term12 - RC*val1[n];

    // term2 = val(x2) - payoff
    float prod = 1.f;
    for (int k=0;k<DIMN;k++) prod *= inputs[(NN + n)*DD + k];
    float payoff = powf(prod, 1.0f/(float)DIMN);
    if (!(payoff > 0.f)) payoff = 0.f;
    out[NN + n] = val2[n] - payoff;
}

extern "C" void kernel_launch(void* const* d_in, const int* in_sizes, int n_in,
                              void* d_out, int out_size, void* d_ws, size_t ws_size,
                              hipStream_t stream)
{
    const float* inputs = (const float*)d_in[0];
    const float* eps    = (const float*)d_in[1];
    const float* w1     = (const float*)d_in[2];
    const float* b1     = (const float*)d_in[3];
    const float* uz     = (const float*)d_in[4];
    const float* wz     = (const float*)d_in[5];
    const float* bz     = (const float*)d_in[6];
    const float* ug     = (const float*)d_in[7];
    const float* wg     = (const float*)d_in[8];
    const float* bg     = (const float*)d_in[9];
    const float* urr    = (const float*)d_in[10];
    const float* wr     = (const float*)d_in[11];
    const float* br     = (const float*)d_in[12];
    const float* uh     = (const float*)d_in[13];
    const float* wh     = (const float*)d_in[14];
    const float* bh     = (const float*)d_in[15];
    const float* wv     = (const float*)d_in[16];
    const float* bv     = (const float*)d_in[17];

    float* ws   = (float*)d_ws;
    float* Lm   = ws + OFF_L;
    float* WT   = ws + OFF_WT;
    float* fp1  = ws + OFF_FP1;
    float* val1 = ws + OFF_VAL1;
    float* val2 = ws + OFF_VAL2;
    float* t12  = ws + OFF_T12;
    float* out  = (float*)d_out;

    hipMemsetAsync(t12, 0, NN*sizeof(float), stream);
    hipLaunchKernelGGL(chol_kernel, dim3(1), dim3(64), 0, stream, Lm);
    hipLaunchKernelGGL(transpose_k, dim3(256), dim3(256), 0, stream, wz, wg, wr, wh, WT);
    hipLaunchKernelGGL(dgm_main, dim3(NBLK), dim3(256), 0, stream,
        inputs, eps, w1, b1, uz, wz, bz, ug, wg, bg, urr, wr, br, uh, wh, bh, wv, bv,
        Lm, WT, fp1, val1, val2, t12);
    hipLaunchKernelGGL(finalize_k, dim3(8), dim3(256), 0, stream,
        inputs, eps, Lm, fp1, val1, val2, t12, out);
}

// Round 2
// 4635.389 us; speedup vs baseline: 4.7318x; 4.7318x over previous
//
#include <hip/hip_runtime.h>
#include <math.h>

#define DIMN 20
#define DD 21
#define NN 2048
#define MCN 32
#define UNITS 128
#define SIGC 0.2f
#define MUC 0.05f
#define RC 0.05f
#define DELTAC 0.01f

#define TM 32
#define KCH 8
#define PTOT (NN + MCN*NN + NN)
#define NBLK (PTOT/TM)

// ws layout (floats)
#define OFF_L 0
#define OFF_WT 512
#define OFF_FP1 (512 + 4*16384)
#define OFF_VAL1 (OFF_FP1 + NN*DD)
#define OFF_VAL2 (OFF_VAL1 + NN)
#define OFF_T12  (OFF_VAL2 + NN)

// LDS layout (floats)
#define L_SA 0
#define L_SB 4096
#define L_SC 8192
#define L_D  12288
#define L_WC 16384
#define L_XT 18432
#define L_TOT 19104

__device__ __forceinline__ int offq(int row, int p0){
    return row*32 + ((p0 + 4*(row&7)) & 31);
}
__device__ __forceinline__ int offs(int row, int p){
    return row*32 + (((p & 28) + 4*(row&7)) & 31) + (p & 3);
}

// stage `units` 16B-units from global g into contiguous LDS wc (row-major chunk)
__device__ __forceinline__ void stageW(const float* __restrict__ g, float* wc, int units){
#if defined(__has_builtin) && __has_builtin(__builtin_amdgcn_global_load_lds)
    int lane = threadIdx.x & 63, wid = threadIdx.x >> 6;
    for (int base = wid*64; base < units; base += 256){
        int u = base + lane;
        if (u < units)
            __builtin_amdgcn_global_load_lds(
                (const __attribute__((address_space(1))) unsigned int*)(g) + (size_t)u*4,
                (__attribute__((address_space(3))) unsigned int*)(wc) + (size_t)base*4,
                16, 0, 0);
    }
#else
    int t = threadIdx.x;
    for (int u = t; u < units; u += 256){
        float4 v = *(const float4*)(g + u*4);
        *(float4*)(wc + u*4) = v;
    }
#endif
}

#define FMA16(acc, s4, w4) \
  acc[0][0]=fmaf(s4.x,w4.x,acc[0][0]); acc[0][1]=fmaf(s4.x,w4.y,acc[0][1]); \
  acc[0][2]=fmaf(s4.x,w4.z,acc[0][2]); acc[0][3]=fmaf(s4.x,w4.w,acc[0][3]); \
  acc[1][0]=fmaf(s4.y,w4.x,acc[1][0]); acc[1][1]=fmaf(s4.y,w4.y,acc[1][1]); \
  acc[1][2]=fmaf(s4.y,w4.z,acc[1][2]); acc[1][3]=fmaf(s4.y,w4.w,acc[1][3]); \
  acc[2][0]=fmaf(s4.z,w4.x,acc[2][0]); acc[2][1]=fmaf(s4.z,w4.y,acc[2][1]); \
  acc[2][2]=fmaf(s4.z,w4.z,acc[2][2]); acc[2][3]=fmaf(s4.z,w4.w,acc[2][3]); \
  acc[3][0]=fmaf(s4.w,w4.x,acc[3][0]); acc[3][1]=fmaf(s4.w,w4.y,acc[3][1]); \
  acc[3][2]=fmaf(s4.w,w4.z,acc[3][2]); acc[3][3]=fmaf(s4.w,w4.w,acc[3][3]);

// acc[p][jj] += sum_k vec[k][p0+p] * W[k][4jg+jj], K rows, double-buffered LDS W chunks
__device__ __forceinline__ void mm_acc(const float* __restrict__ gW, int K,
    const float* __restrict__ vec, float acc[4][4], float* __restrict__ Wc,
    int jg, int p0)
{
    int nch = (K + KCH - 1) / KCH;
    {
        int r0 = (K < KCH) ? K : KCH;
        stageW(gW, Wc, r0*32);
    }
    for (int c = 0; c < nch; c++){
        __syncthreads();          // stage(c) done; compute(c-1) done everywhere
        if (c + 1 < nch){
            int c0n = (c+1)*KCH;
            int rn = K - c0n; if (rn > KCH) rn = KCH;
            stageW(gW + c0n*UNITS, Wc + ((c+1)&1)*KCH*UNITS, rn*32);
        }
        int c0 = c*KCH;
        int rows = K - c0; if (rows > KCH) rows = KCH;
        const float* wb = Wc + (c&1)*KCH*UNITS;
        if (rows == KCH){
            #pragma unroll
            for (int kk = 0; kk < KCH; kk++){
                int k = c0 + kk;
                float4 w4 = *(const float4*)(wb + kk*UNITS + 4*jg);
                float4 s4 = *(const float4*)(vec + offq(k, p0));
                FMA16(acc, s4, w4)
            }
        } else {
            for (int kk = 0; kk < rows; kk++){
                int k = c0 + kk;
                float4 w4 = *(const float4*)(wb + kk*UNITS + 4*jg);
                float4 s4 = *(const float4*)(vec + offq(k, p0));
                FMA16(acc, s4, w4)
            }
        }
    }
    __syncthreads();              // last compute done before Wc/vec reuse
}

__device__ __forceinline__ void write_own(float* buf, const float v[4][4], int j0, int p0){
    #pragma unroll
    for (int jj = 0; jj < 4; jj++){
        int j = j0 + jj;
        float4 q = make_float4(v[0][jj], v[1][jj], v[2][jj], v[3][jj]);
        *(float4*)(buf + offq(j, p0)) = q;
    }
}
__device__ __forceinline__ void read_own(const float* buf, float v[4][4], int j0, int p0){
    #pragma unroll
    for (int jj = 0; jj < 4; jj++){
        int j = j0 + jj;
        float4 q = *(const float4*)(buf + offq(j, p0));
        v[0][jj]=q.x; v[1][jj]=q.y; v[2][jj]=q.z; v[3][jj]=q.w;
    }
}

// out = tanh(bias + x@U + vec@W)
__device__ __forceinline__ void gate_f(const float* __restrict__ U, const float* __restrict__ W,
    const float* __restrict__ bias, const float* __restrict__ xT, const float* __restrict__ Sin,
    float* __restrict__ Wc, float out[4][4], int jg, int p0, int j0)
{
    float acc[4][4];
    float4 b = *(const float4*)(bias + j0);
    #pragma unroll
    for (int p = 0; p < 4; p++){ acc[p][0]=b.x; acc[p][1]=b.y; acc[p][2]=b.z; acc[p][3]=b.w; }
    mm_acc(U, DD, xT, acc, Wc, jg, p0);
    mm_acc(W, UNITS, Sin, acc, Wc, jg, p0);
    #pragma unroll
    for (int p = 0; p < 4; p++)
        #pragma unroll
        for (int jj = 0; jj < 4; jj++) out[p][jj] = tanhf(acc[p][jj]);
}

__global__ void chol_kernel(float* __restrict__ Lout)
{
    if (threadIdx.x == 0 && blockIdx.x == 0) {
        double Lc[DIMN][DIMN];
        for (int i = 0; i < DIMN; i++)
            for (int j = 0; j <= i; j++) {
                double s = 0.01 * (0.5 + (i == j ? 0.5 : 0.0));
                for (int t2 = 0; t2 < j; t2++) s -= Lc[i][t2] * Lc[j][t2];
                Lc[i][j] = (i == j) ? sqrt(s) : s / Lc[j][j];
            }
        for (int i = 0; i < DIMN; i++)
            for (int j = 0; j < DIMN; j++)
                Lout[i*DIMN + j] = (j <= i) ? (float)Lc[i][j] : 0.0f;
    }
}

__global__ void transpose_k(const float* __restrict__ wz, const float* __restrict__ wg,
                            const float* __restrict__ wr, const float* __restrict__ wh,
                            float* __restrict__ WT)
{
    int idx = blockIdx.x*256 + threadIdx.x;           // 0..65535
    int q = idx >> 14, r2 = idx & 16383, k = r2 >> 7, j = r2 & 127;
    const float* src = (q==0)? wz : (q==1)? wg : (q==2)? wr : wh;
    WT[(q<<14) + j*UNITS + k] = src[k*UNITS + j];
}

__global__ __launch_bounds__(256, 2) void dgm_main(
    const float* __restrict__ inputs, const float* __restrict__ eps,
    const float* __restrict__ w1, const float* __restrict__ b1,
    const float* __restrict__ uz, const float* __restrict__ wz, const float* __restrict__ bz,
    const float* __restrict__ ug, const float* __restrict__ wg, const float* __restrict__ bg,
    const float* __restrict__ ur, const float* __restrict__ wr, const float* __restrict__ br,
    const float* __restrict__ uh, const float* __restrict__ wh, const float* __restrict__ bh,
    const float* __restrict__ wv, const float* __restrict__ bv,
    const float* __restrict__ Lm, const float* __restrict__ WT,
    float* __restrict__ fp1, float* __restrict__ val1, float* __restrict__ val2,
    float* __restrict__ t12acc)
{
    __shared__ float lds[L_TOT];
    float* SBUF0 = lds + L_SA;
    float* SBUF1 = lds + L_SB;
    float* SBUF2 = lds + L_SC;
    float* Db    = lds + L_D;
    float* Wc    = lds + L_WC;
    float* xT    = lds + L_XT;
    float* SBUF[3] = {SBUF0, SBUF1, SBUF2};

    const int t  = threadIdx.x;
    const int jg = t & 31;
    const int pg = t >> 5;
    const int p0 = pg * 4;
    const int j0 = jg * 4;
    const int P0 = blockIdx.x * TM;
    const int type = (P0 < NN) ? 0 : (P0 < NN + MCN*NN) ? 1 : 2;
    int base_n = 0, mrow = 0;
    if (type == 1){ int q = P0 - NN; mrow = q >> 11; base_n = q & (NN-1); }

    // ---- build x tile ----
    {
        int p = t & 31, kq = t >> 5;
        for (int ki = 0; ki < 3; ki++){
            int k = kq + 8*ki;
            if (k > DIMN) break;
            float xv;
            if (type == 0){
                xv = inputs[(P0 + p)*DD + k];
            } else if (type == 2){
                xv = inputs[(NN + (P0 - NN - MCN*NN) + p)*DD + k];
            } else {
                int n = base_n + p;
                float x1v = inputs[n*DD + k];
                if (k == DIMN) xv = x1v;
                else {
                    const float* ep = eps + (size_t)(mrow*NN + n)*DIMN;
                    float a = x1v;
                    for (int d = 0; d < DIMN; d++) a = fmaf(ep[d], Lm[k*DIMN + d], a);
                    xv = x1v + a * (SIGC * x1v);
                }
            }
            xT[offs(k, p)] = xv;
        }
    }
    // (mm_acc's first sync covers visibility of xT)

    // ---- forward ----
    float s_own[4][4];
    {
        float acc[4][4];
        float4 b = *(const float4*)(b1 + j0);
        #pragma unroll
        for (int p = 0; p < 4; p++){ acc[p][0]=b.x; acc[p][1]=b.y; acc[p][2]=b.z; acc[p][3]=b.w; }
        mm_acc(w1, DD, xT, acc, Wc, jg, p0);
        #pragma unroll
        for (int p = 0; p < 4; p++)
            #pragma unroll
            for (int jj = 0; jj < 4; jj++) s_own[p][jj] = tanhf(acc[p][jj]);
        write_own(SBUF0, s_own, j0, p0);
    }

    float zt[4][4], gt[4][4], rt[4][4], ht[4][4];
    for (int L = 0; L < 3; L++){
        gate_f(uz, wz, bz, xT, SBUF[L], Wc, zt, jg, p0, j0);
        gate_f(ug, wg, bg, xT, SBUF[L], Wc, gt, jg, p0, j0);
        gate_f(ur, wr, br, xT, SBUF[L], Wc, rt, jg, p0, j0);
        {
            float tt[4][4];
            #pragma unroll
            for (int p = 0; p < 4; p++)
                #pragma unroll
                for (int jj = 0; jj < 4; jj++) tt[p][jj] = s_own[p][jj]*rt[p][jj];
            write_own(Db, tt, j0, p0);
        }
        gate_f(uh, wh, bh, xT, Db, Wc, ht, jg, p0, j0);
        #pragma unroll
        for (int p = 0; p < 4; p++)
            #pragma unroll
            for (int jj = 0; jj < 4; jj++)
                s_own[p][jj] = (1.f - gt[p][jj])*ht[p][jj] + zt[p][jj]*s_own[p][jj];
        if (L < 2) write_own(SBUF[L+1], s_own, j0, p0);
    }

    // ---- value head ----
    {
        float4 wv4 = *(const float4*)(wv + j0);
        float vs[4];
        #pragma unroll
        for (int p = 0; p < 4; p++)
            vs[p] = s_own[p][0]*wv4.x + s_own[p][1]*wv4.y + s_own[p][2]*wv4.z + s_own[p][3]*wv4.w;
        *(float4*)(Db + jg*32 + p0) = make_float4(vs[0], vs[1], vs[2], vs[3]);
        __syncthreads();
        if (t < TM){
            float v = bv[0];
            for (int j2 = 0; j2 < 32; j2++) v += Db[j2*32 + t];
            if (type == 0) val1[P0 + t] = v;
            else if (type == 2) val2[P0 + t - NN - MCN*NN] = v;
        }
        __syncthreads();
    }
    if (type == 2) return;

    // ---- backward ----
    float ds[4][4];
    {
        float4 wv4 = *(const float4*)(wv + j0);
        #pragma unroll
        for (int p = 0; p < 4; p++){ ds[p][0]=wv4.x; ds[p][1]=wv4.y; ds[p][2]=wv4.z; ds[p][3]=wv4.w; }
    }
    float dga_z[4][4], dga_g[4][4], dga_r[4][4], dga_h[4][4], v0[4][4];
    #pragma unroll
    for (int p = 0; p < 4; p++)
        #pragma unroll
        for (int jj = 0; jj < 4; jj++){ dga_z[p][jj]=0.f; dga_g[p][jj]=0.f; dga_r[p][jj]=0.f; dga_h[p][jj]=0.f; }

    const float* WTz = WT;
    const float* WTg = WT + 16384;
    const float* WTr = WT + 2*16384;
    const float* WTh = WT + 3*16384;

    for (int L = 2; L >= 0; L--){
        float sl[4][4];
        read_own(SBUF[L], sl, j0, p0);
        gate_f(uz, wz, bz, xT, SBUF[L], Wc, zt, jg, p0, j0);
        gate_f(ug, wg, bg, xT, SBUF[L], Wc, gt, jg, p0, j0);
        gate_f(ur, wr, br, xT, SBUF[L], Wc, rt, jg, p0, j0);
        {
            float tt[4][4];
            #pragma unroll
            for (int p = 0; p < 4; p++)
                #pragma unroll
                for (int jj = 0; jj < 4; jj++) tt[p][jj] = sl[p][jj]*rt[p][jj];
            write_own(Db, tt, j0, p0);
        }
        gate_f(uh, wh, bh, xT, Db, Wc, ht, jg, p0, j0);

        float dhp[4][4], dzp[4][4], dgp[4][4], dsn[4][4];
        #pragma unroll
        for (int p = 0; p < 4; p++)
            #pragma unroll
            for (int jj = 0; jj < 4; jj++){
                float d = ds[p][jj], g = gt[p][jj], h = ht[p][jj], z = zt[p][jj], s = sl[p][jj];
                dhp[p][jj] = d*(1.f - g)*(1.f - h*h);
                dgp[p][jj] = -d*h*(1.f - g*g);
                dzp[p][jj] = d*s*(1.f - z*z);
                dsn[p][jj] = d*z;
                dga_h[p][jj] += dhp[p][jj];
                dga_g[p][jj] += dgp[p][jj];
                dga_z[p][jj] += dzp[p][jj];
            }
        write_own(Db, dhp, j0, p0);
        float dsr[4][4];
        #pragma unroll
        for (int p = 0; p < 4; p++)
            #pragma unroll
            for (int jj = 0; jj < 4; jj++) dsr[p][jj] = 0.f;
        mm_acc(WTh, UNITS, Db, dsr, Wc, jg, p0);
        {
            float drp[4][4];
            #pragma unroll
            for (int p = 0; p < 4; p++)
                #pragma unroll
                for (int jj = 0; jj < 4; jj++){
                    float dr = dsr[p][jj], r = rt[p][jj], s = sl[p][jj];
                    drp[p][jj] = dr*s*(1.f - r*r);
                    dga_r[p][jj] += drp[p][jj];
                    dsn[p][jj] += dr*r;
                }
            write_own(Db, dzp, j0, p0);
            mm_acc(WTz, UNITS, Db, dsn, Wc, jg, p0);
            write_own(Db, dgp, j0, p0);
            mm_acc(WTg, UNITS, Db, dsn, Wc, jg, p0);
            write_own(Db, drp, j0, p0);
            mm_acc(WTr, UNITS, Db, dsn, Wc, jg, p0);
        }
        #pragma unroll
        for (int p = 0; p < 4; p++)
            #pragma unroll
            for (int jj = 0; jj < 4; jj++) ds[p][jj] = dsn[p][jj];
    }
    // first layer backward
    {
        float s0l[4][4];
        read_own(SBUF0, s0l, j0, p0);
        #pragma unroll
        for (int p = 0; p < 4; p++)
            #pragma unroll
            for (int jj = 0; jj < 4; jj++)
                v0[p][jj] = ds[p][jj]*(1.f - s0l[p][jj]*s0l[p][jj]);
    }

    if (type == 1){
        // rebuild violation V into Db rows 0..19 (k-major, swizzled)
        {
            int p = t & 31, kq = t >> 5;
            for (int ki = 0; ki < 3; ki++){
                int k = kq + 8*ki;
                if (k >= DIMN) break;
                int n = base_n + p;
                float x1v = inputs[n*DD + k];
                const float* ep = eps + (size_t)(mrow*NN + n)*DIMN;
                float a = x1v;
                for (int d = 0; d < DIMN; d++) a = fmaf(ep[d], Lm[k*DIMN + d], a);
                Db[offs(k, p)] = a * (SIGC * x1v);
            }
        }
        float proj[4] = {0.f, 0.f, 0.f, 0.f};
        const float* Ulist[5] = {uz, ug, ur, uh, w1};
        for (int g5 = 0; g5 < 5; g5++){
            float uv[4][4];
            #pragma unroll
            for (int p = 0; p < 4; p++)
                #pragma unroll
                for (int jj = 0; jj < 4; jj++) uv[p][jj] = 0.f;
            mm_acc(Ulist[g5], DIMN, Db, uv, Wc, jg, p0);
            const float (*sel)[4] = (g5==0)? dga_z : (g5==1)? dga_g : (g5==2)? dga_r : (g5==3)? dga_h : v0;
            #pragma unroll
            for (int p = 0; p < 4; p++)
                #pragma unroll
                for (int jj = 0; jj < 4; jj++) proj[p] += uv[p][jj]*sel[p][jj];
        }
        // reduce over jg: scratch rows 24..55 of Db (plain layout, disjoint from V rows)
        *(float4*)(Db + (24 + jg)*32 + p0) = make_float4(proj[0], proj[1], proj[2], proj[3]);
        __syncthreads();
        if (t < TM){
            float s = 0.f;
            for (int j2 = 0; j2 < 32; j2++) s += Db[(24 + j2)*32 + t];
            atomicAdd(t12acc + base_n + t, s);
        }
    } else {
        // type 0: full fprime
        float dxp[3] = {0.f, 0.f, 0.f};
        int pi = t >> 3, il = t & 7;
        const float* Ulist[5] = {uz, ug, ur, uh, w1};
        for (int g5 = 0; g5 < 5; g5++){
            __syncthreads();
            {
                float w44[4][4];
                const float (*sel)[4] = (g5==0)? dga_z : (g5==1)? dga_g : (g5==2)? dga_r : (g5==3)? dga_h : v0;
                #pragma unroll
                for (int p = 0; p < 4; p++)
                    #pragma unroll
                    for (int jj = 0; jj < 4; jj++) w44[p][jj] = sel[p][jj];
                write_own(Db, w44, j0, p0);
            }
            __syncthreads();
            for (int ii = 0; ii < 3; ii++){
                int i = il + 8*ii;
                if (i >= DD) break;
                const float* Urow = Ulist[g5] + i*UNITS;
                float a = 0.f;
                for (int j2 = 0; j2 < UNITS; j2++) a = fmaf(Db[offs(j2, pi)], Urow[j2], a);
                dxp[ii] += a;
            }
        }
        for (int ii = 0; ii < 3; ii++){
            int i = il + 8*ii;
            if (i < DD) fp1[(P0 + pi)*DD + i] = dxp[ii];
        }
    }
}

__global__ void finalize_k(const float* __restrict__ inputs, const float* __restrict__ eps,
    const float* __restrict__ Lm, const float* __restrict__ fp1, const float* __restrict__ val1,
    const float* __restrict__ val2, const float* __restrict__ t12acc, float* __restrict__ out)
{
    int n = blockIdx.x*256 + threadIdx.x;
    if (n >= NN) return;
    float fp[DD];
    for (int k = 0; k < DD; k++) fp[k] = fp1[n*DD + k];
    float t11 = fp[DIMN];
    for (int k = 0; k < DIMN; k++) t11 = fmaf(MUC*inputs[n*DD + k], fp[k], t11);
    float esum[DIMN];
    for (int d = 0; d < DIMN; d++){
        float a = 0.f;
        for (int m = 0; m < MCN; m++) a += eps[(size_t)(m*NN + n)*DIMN + d];
        esum[d] = a;
    }
    float t12b = 0.f;
    for (int k = 0; k < DIMN; k++){
        float loc = inputs[n*DD + k];
        float ssum = (float)MCN * loc;
        for (int d = 0; d < DIMN; d++) ssum = fmaf(esum[d], Lm[k*DIMN + d], ssum);
        float vsum = ssum * (SIGC*loc);
        t12b = fmaf(fp[k], vsum, t12b);
    }
    float term12 = (t12acc[n] - t12b) * (1.0f/(DELTAC*(float)MCN));
    out[n] = t11 + 0.5f*term12 - RC*val1[n];

    float prod = 1.f;
    for (int k = 0; k < DIMN; k++) prod *= inputs[(NN + n)*DD + k];
    float payoff = powf(prod, 1.0f/(float)DIMN);
    if (!(payoff > 0.f)) payoff = 0.f;
    out[NN + n] = val2[n] - payoff;
}

extern "C" void kernel_launch(void* const* d_in, const int* in_sizes, int n_in,
                              void* d_out, int out_size, void* d_ws, size_t ws_size,
                              hipStream_t stream)
{
    const float* inputs = (const float*)d_in[0];
    const float* eps    = (const float*)d_in[1];
    const float* w1     = (const float*)d_in[2];
    const float* b1     = (const float*)d_in[3];
    const float* uz     = (const float*)d_in[4];
    const float* wz     = (const float*)d_in[5];
    const float* bz     = (const float*)d_in[6];
    const float* ug     = (const float*)d_in[7];
    const float* wg     = (const float*)d_in[8];
    const float* bg     = (const float*)d_in[9];
    const float* urr    = (const float*)d_in[10];
    const float* wr     = (const float*)d_in[11];
    const float* br     = (const float*)d_in[12];
    const float* uh     = (const float*)d_in[13];
    const float* wh     = (const float*)d_in[14];
    const float* bh     = (const float*)d_in[15];
    const float* wv     = (const float*)d_in[16];
    const float* bv     = (const float*)d_in[17];

    float* ws   = (float*)d_ws;
    float* Lm   = ws + OFF_L;
    float* WT   = ws + OFF_WT;
    float* fp1  = ws + OFF_FP1;
    float* val1 = ws + OFF_VAL1;
    float* val2 = ws + OFF_VAL2;
    float* t12  = ws + OFF_T12;
    float* out  = (float*)d_out;

    hipMemsetAsync(t12, 0, NN*sizeof(float), stream);
    hipLaunchKernelGGL(chol_kernel, dim3(1), dim3(64), 0, stream, Lm);
    hipLaunchKernelGGL(transpose_k, dim3(256), dim3(256), 0, stream, wz, wg, wr, wh, WT);
    hipLaunchKernelGGL(dgm_main, dim3(NBLK), dim3(256), 0, stream,
        inputs, eps, w1, b1, uz, wz, bz, ug, wg, bg, urr, wr, br, uh, wh, bh, wv, bv,
        Lm, WT, fp1, val1, val2, t12);
    hipLaunchKernelGGL(finalize_k, dim3(8), dim3(256), 0, stream,
        inputs, eps, Lm, fp1, val1, val2, t12, out);
}

// Round 3
// 2414.714 us; speedup vs baseline: 9.0834x; 1.9196x over previous
//
#include <hip/hip_runtime.h>
#include <math.h>

#define DIMN 20
#define DD 21
#define NN 2048
#define MCN 32
#define UNITS 128
#define SIGC 0.2f
#define MUC 0.05f
#define RC 0.05f
#define DELTAC 0.01f

#define TM 32
#define KCH 8
#define PTOT (NN + MCN*NN + NN)
#define NBLK (PTOT/TM)

// ws layout (floats)
#define OFF_L 0
#define OFF_WT 512
#define OFF_FP1 (512 + 4*16384)
#define OFF_VAL1 (OFF_FP1 + NN*DD)
#define OFF_VAL2 (OFF_VAL1 + NN)
#define OFF_T12  (OFF_VAL2 + NN)

// LDS layout (floats)
#define L_SA 0
#define L_SB 4096
#define L_SC 8192
#define L_D  12288
#define L_WC 16384
#define L_XT 18432
#define L_TOT 19104

#define ELT44(...) _Pragma("unroll") for (int p = 0; p < 4; p++){ _Pragma("unroll") for (int jj = 0; jj < 4; jj++){ __VA_ARGS__; } }

__device__ __forceinline__ int offq(int row, int p0){
    return row*32 + ((p0 + 4*(row&7)) & 31);
}
__device__ __forceinline__ int offs(int row, int p){
    return row*32 + (((p & 28) + 4*(row&7)) & 31) + (p & 3);
}

// stage `units` 16B-units from global g into contiguous LDS wc (row-major chunk)
__device__ __forceinline__ void stageW(const float* __restrict__ g, float* wc, int units){
#if defined(__has_builtin) && __has_builtin(__builtin_amdgcn_global_load_lds)
    int lane = threadIdx.x & 63, wid = threadIdx.x >> 6;
    for (int base = wid*64; base < units; base += 256){
        int u = base + lane;
        if (u < units)
            __builtin_amdgcn_global_load_lds(
                (const __attribute__((address_space(1))) unsigned int*)(g) + (size_t)u*4,
                (__attribute__((address_space(3))) unsigned int*)(wc) + (size_t)base*4,
                16, 0, 0);
    }
#else
    int t = threadIdx.x;
    for (int u = t; u < units; u += 256){
        float4 v = *(const float4*)(g + u*4);
        *(float4*)(wc + u*4) = v;
    }
#endif
}

#define FMA16(acc, s4, w4) \
  acc[0][0]=fmaf(s4.x,w4.x,acc[0][0]); acc[0][1]=fmaf(s4.x,w4.y,acc[0][1]); \
  acc[0][2]=fmaf(s4.x,w4.z,acc[0][2]); acc[0][3]=fmaf(s4.x,w4.w,acc[0][3]); \
  acc[1][0]=fmaf(s4.y,w4.x,acc[1][0]); acc[1][1]=fmaf(s4.y,w4.y,acc[1][1]); \
  acc[1][2]=fmaf(s4.y,w4.z,acc[1][2]); acc[1][3]=fmaf(s4.y,w4.w,acc[1][3]); \
  acc[2][0]=fmaf(s4.z,w4.x,acc[2][0]); acc[2][1]=fmaf(s4.z,w4.y,acc[2][1]); \
  acc[2][2]=fmaf(s4.z,w4.z,acc[2][2]); acc[2][3]=fmaf(s4.z,w4.w,acc[2][3]); \
  acc[3][0]=fmaf(s4.w,w4.x,acc[3][0]); acc[3][1]=fmaf(s4.w,w4.y,acc[3][1]); \
  acc[3][2]=fmaf(s4.w,w4.z,acc[3][2]); acc[3][3]=fmaf(s4.w,w4.w,acc[3][3]);

// acc[p][jj] += sum_k vec[k][p0+p] * W[k][4jg+jj], K rows, double-buffered LDS W chunks
__device__ __forceinline__ void mm_acc(const float* __restrict__ gW, int K,
    const float* __restrict__ vec, float acc[4][4], float* __restrict__ Wc,
    int jg, int p0)
{
    int nch = (K + KCH - 1) / KCH;
    {
        int r0 = (K < KCH) ? K : KCH;
        stageW(gW, Wc, r0*32);
    }
    for (int c = 0; c < nch; c++){
        __syncthreads();          // stage(c) done; compute(c-1) done everywhere
        if (c + 1 < nch){
            int c0n = (c+1)*KCH;
            int rn = K - c0n; if (rn > KCH) rn = KCH;
            stageW(gW + c0n*UNITS, Wc + ((c+1)&1)*KCH*UNITS, rn*32);
        }
        int c0 = c*KCH;
        int rows = K - c0; if (rows > KCH) rows = KCH;
        const float* wb = Wc + (c&1)*KCH*UNITS;
        if (rows == KCH){
            #pragma unroll
            for (int kk = 0; kk < KCH; kk++){
                int k = c0 + kk;
                float4 w4 = *(const float4*)(wb + kk*UNITS + 4*jg);
                float4 s4 = *(const float4*)(vec + offq(k, p0));
                FMA16(acc, s4, w4)
            }
        } else {
            for (int kk = 0; kk < rows; kk++){
                int k = c0 + kk;
                float4 w4 = *(const float4*)(wb + kk*UNITS + 4*jg);
                float4 s4 = *(const float4*)(vec + offq(k, p0));
                FMA16(acc, s4, w4)
            }
        }
    }
    __syncthreads();              // last compute done before Wc/vec reuse
}

__device__ __forceinline__ void write_own(float* buf, const float v[4][4], int j0, int p0){
    #pragma unroll
    for (int jj = 0; jj < 4; jj++){
        int j = j0 + jj;
        float4 q = make_float4(v[0][jj], v[1][jj], v[2][jj], v[3][jj]);
        *(float4*)(buf + offq(j, p0)) = q;
    }
}
__device__ __forceinline__ void read_own(const float* buf, float v[4][4], int j0, int p0){
    #pragma unroll
    for (int jj = 0; jj < 4; jj++){
        int j = j0 + jj;
        float4 q = *(const float4*)(buf + offq(j, p0));
        v[0][jj]=q.x; v[1][jj]=q.y; v[2][jj]=q.z; v[3][jj]=q.w;
    }
}

// out = tanh(bias + x@U + vec@W)
__device__ __forceinline__ void gate_f(const float* __restrict__ U, const float* __restrict__ W,
    const float* __restrict__ bias, const float* __restrict__ xT, const float* __restrict__ Sin,
    float* __restrict__ Wc, float out[4][4], int jg, int p0, int j0)
{
    float acc[4][4];
    float4 b = *(const float4*)(bias + j0);
    #pragma unroll
    for (int p = 0; p < 4; p++){ acc[p][0]=b.x; acc[p][1]=b.y; acc[p][2]=b.z; acc[p][3]=b.w; }
    mm_acc(U, DD, xT, acc, Wc, jg, p0);
    mm_acc(W, UNITS, Sin, acc, Wc, jg, p0);
    #pragma unroll
    for (int p = 0; p < 4; p++)
        #pragma unroll
        for (int jj = 0; jj < 4; jj++) out[p][jj] = tanhf(acc[p][jj]);
}

__global__ void chol_kernel(float* __restrict__ Lout)
{
    if (threadIdx.x == 0 && blockIdx.x == 0) {
        double Lc[DIMN][DIMN];
        for (int i = 0; i < DIMN; i++)
            for (int j = 0; j <= i; j++) {
                double s = 0.01 * (0.5 + (i == j ? 0.5 : 0.0));
                for (int t2 = 0; t2 < j; t2++) s -= Lc[i][t2] * Lc[j][t2];
                Lc[i][j] = (i == j) ? sqrt(s) : s / Lc[j][j];
            }
        for (int i = 0; i < DIMN; i++)
            for (int j = 0; j < DIMN; j++)
                Lout[i*DIMN + j] = (j <= i) ? (float)Lc[i][j] : 0.0f;
    }
}

__global__ void transpose_k(const float* __restrict__ wz, const float* __restrict__ wg,
                            const float* __restrict__ wr, const float* __restrict__ wh,
                            float* __restrict__ WT)
{
    int idx = blockIdx.x*256 + threadIdx.x;           // 0..65535
    int q = idx >> 14, r2 = idx & 16383, k = r2 >> 7, j = r2 & 127;
    const float* src = (q==0)? wz : (q==1)? wg : (q==2)? wr : wh;
    WT[(q<<14) + j*UNITS + k] = src[k*UNITS + j];
}

__global__ __launch_bounds__(256, 2) void dgm_main(
    const float* __restrict__ inputs, const float* __restrict__ eps,
    const float* __restrict__ w1, const float* __restrict__ b1,
    const float* __restrict__ uz, const float* __restrict__ wz, const float* __restrict__ bz,
    const float* __restrict__ ug, const float* __restrict__ wg, const float* __restrict__ bg,
    const float* __restrict__ ur, const float* __restrict__ wr, const float* __restrict__ br,
    const float* __restrict__ uh, const float* __restrict__ wh, const float* __restrict__ bh,
    const float* __restrict__ wv, const float* __restrict__ bv,
    const float* __restrict__ Lm, const float* __restrict__ WT,
    float* __restrict__ fp1, float* __restrict__ val1, float* __restrict__ val2,
    float* __restrict__ t12acc)
{
    __shared__ float lds[L_TOT];
    float* SBUF0 = lds + L_SA;
    float* SBUF1 = lds + L_SB;
    float* SBUF2 = lds + L_SC;
    float* Db    = lds + L_D;
    float* Wc    = lds + L_WC;
    float* xT    = lds + L_XT;

    const int t  = threadIdx.x;
    const int jg = t & 31;
    const int pg = t >> 5;
    const int p0 = pg * 4;
    const int j0 = jg * 4;
    const int P0 = blockIdx.x * TM;
    const int type = (P0 < NN) ? 0 : (P0 < NN + MCN*NN) ? 1 : 2;
    int base_n = 0, mrow = 0;
    if (type == 1){ int q = P0 - NN; mrow = q >> 11; base_n = q & (NN-1); }

    // ---- build x tile ----
    {
        int p = t & 31, kq = t >> 5;
        for (int ki = 0; ki < 3; ki++){
            int k = kq + 8*ki;
            if (k > DIMN) break;
            float xv;
            if (type == 0){
                xv = inputs[(P0 + p)*DD + k];
            } else if (type == 2){
                xv = inputs[(NN + (P0 - NN - MCN*NN) + p)*DD + k];
            } else {
                int n = base_n + p;
                float x1v = inputs[n*DD + k];
                if (k == DIMN) xv = x1v;
                else {
                    const float* ep = eps + (size_t)(mrow*NN + n)*DIMN;
                    float a = x1v;
                    for (int d = 0; d < DIMN; d++) a = fmaf(ep[d], Lm[k*DIMN + d], a);
                    xv = x1v + a * (SIGC * x1v);
                }
            }
            xT[offs(k, p)] = xv;
        }
    }
    // (mm_acc's first sync covers visibility of xT)

    // ---- forward ----
    float s_own[4][4];
    {
        float acc[4][4];
        float4 b = *(const float4*)(b1 + j0);
        #pragma unroll
        for (int p = 0; p < 4; p++){ acc[p][0]=b.x; acc[p][1]=b.y; acc[p][2]=b.z; acc[p][3]=b.w; }
        mm_acc(w1, DD, xT, acc, Wc, jg, p0);
        ELT44(s_own[p][jj] = tanhf(acc[p][jj]))
        write_own(SBUF0, s_own, j0, p0);
    }

    float zt[4][4], gt[4][4], rt[4][4], ht[4][4];

#define FWD_LAYER(SIN) \
    gate_f(uz, wz, bz, xT, SIN, Wc, zt, jg, p0, j0); \
    gate_f(ug, wg, bg, xT, SIN, Wc, gt, jg, p0, j0); \
    gate_f(ur, wr, br, xT, SIN, Wc, rt, jg, p0, j0); \
    { float tt[4][4]; ELT44(tt[p][jj] = s_own[p][jj]*rt[p][jj]) write_own(Db, tt, j0, p0); } \
    gate_f(uh, wh, bh, xT, Db, Wc, ht, jg, p0, j0); \
    ELT44(s_own[p][jj] = (1.f - gt[p][jj])*ht[p][jj] + zt[p][jj]*s_own[p][jj])

    FWD_LAYER(SBUF0)
    write_own(SBUF1, s_own, j0, p0);
    FWD_LAYER(SBUF1)
    write_own(SBUF2, s_own, j0, p0);
    FWD_LAYER(SBUF2)

    // ---- value head ----
    {
        float4 wv4 = *(const float4*)(wv + j0);
        float vs[4];
        #pragma unroll
        for (int p = 0; p < 4; p++)
            vs[p] = s_own[p][0]*wv4.x + s_own[p][1]*wv4.y + s_own[p][2]*wv4.z + s_own[p][3]*wv4.w;
        *(float4*)(Db + jg*32 + p0) = make_float4(vs[0], vs[1], vs[2], vs[3]);
        __syncthreads();
        if (t < TM){
            float v = bv[0];
            for (int j2 = 0; j2 < 32; j2++) v += Db[j2*32 + t];
            if (type == 0) val1[P0 + t] = v;
            else if (type == 2) val2[P0 + t - NN - MCN*NN] = v;
        }
        __syncthreads();
    }
    if (type == 2) return;

    // ---- backward ----
    float ds[4][4];
    {
        float4 wv4 = *(const float4*)(wv + j0);
        #pragma unroll
        for (int p = 0; p < 4; p++){ ds[p][0]=wv4.x; ds[p][1]=wv4.y; ds[p][2]=wv4.z; ds[p][3]=wv4.w; }
    }
    float dga_z[4][4], dga_g[4][4], dga_r[4][4], dga_h[4][4], v0[4][4];
    ELT44(dga_z[p][jj]=0.f; dga_g[p][jj]=0.f; dga_r[p][jj]=0.f; dga_h[p][jj]=0.f)

    const float* WTz = WT;
    const float* WTg = WT + 16384;
    const float* WTr = WT + 2*16384;
    const float* WTh = WT + 3*16384;

#define BWD_LAYER(SLBUF) \
    { \
    float sl[4][4]; \
    read_own(SLBUF, sl, j0, p0); \
    gate_f(uz, wz, bz, xT, SLBUF, Wc, zt, jg, p0, j0); \
    gate_f(ug, wg, bg, xT, SLBUF, Wc, gt, jg, p0, j0); \
    gate_f(ur, wr, br, xT, SLBUF, Wc, rt, jg, p0, j0); \
    { float tt[4][4]; ELT44(tt[p][jj] = sl[p][jj]*rt[p][jj]) write_own(Db, tt, j0, p0); } \
    gate_f(uh, wh, bh, xT, Db, Wc, ht, jg, p0, j0); \
    float dhp[4][4]; float dzp[4][4]; float dgp[4][4]; float dsn[4][4]; \
    ELT44(float d=ds[p][jj]; float g=gt[p][jj]; float h=ht[p][jj]; float z=zt[p][jj]; float s=sl[p][jj]; \
        dhp[p][jj] = d*(1.f - g)*(1.f - h*h); \
        dgp[p][jj] = -d*h*(1.f - g*g); \
        dzp[p][jj] = d*s*(1.f - z*z); \
        dsn[p][jj] = d*z; \
        dga_h[p][jj] += dhp[p][jj]; \
        dga_g[p][jj] += dgp[p][jj]; \
        dga_z[p][jj] += dzp[p][jj]) \
    write_own(Db, dhp, j0, p0); \
    float dsr[4][4]; \
    ELT44(dsr[p][jj] = 0.f) \
    mm_acc(WTh, UNITS, Db, dsr, Wc, jg, p0); \
    float drp[4][4]; \
    ELT44(float dr=dsr[p][jj]; float r=rt[p][jj]; float s=sl[p][jj]; \
        drp[p][jj] = dr*s*(1.f - r*r); \
        dga_r[p][jj] += drp[p][jj]; \
        dsn[p][jj] += dr*r) \
    write_own(Db, dzp, j0, p0); \
    mm_acc(WTz, UNITS, Db, dsn, Wc, jg, p0); \
    write_own(Db, dgp, j0, p0); \
    mm_acc(WTg, UNITS, Db, dsn, Wc, jg, p0); \
    write_own(Db, drp, j0, p0); \
    mm_acc(WTr, UNITS, Db, dsn, Wc, jg, p0); \
    ELT44(ds[p][jj] = dsn[p][jj]) \
    }

    BWD_LAYER(SBUF2)
    BWD_LAYER(SBUF1)
    BWD_LAYER(SBUF0)

    // first layer backward
    {
        float s0l[4][4];
        read_own(SBUF0, s0l, j0, p0);
        ELT44(v0[p][jj] = ds[p][jj]*(1.f - s0l[p][jj]*s0l[p][jj]))
    }

    if (type == 1){
        // rebuild violation V into Db rows 0..19 (k-major, swizzled)
        {
            int p = t & 31, kq = t >> 5;
            for (int ki = 0; ki < 3; ki++){
                int k = kq + 8*ki;
                if (k >= DIMN) break;
                int n = base_n + p;
                float x1v = inputs[n*DD + k];
                const float* ep = eps + (size_t)(mrow*NN + n)*DIMN;
                float a = x1v;
                for (int d = 0; d < DIMN; d++) a = fmaf(ep[d], Lm[k*DIMN + d], a);
                Db[offs(k, p)] = a * (SIGC * x1v);
            }
        }
        float proj[4] = {0.f, 0.f, 0.f, 0.f};

#define PROJ_PASS(UMAT, SEL) \
        { float uv[4][4]; \
          ELT44(uv[p][jj] = 0.f) \
          mm_acc(UMAT, DIMN, Db, uv, Wc, jg, p0); \
          ELT44(proj[p] += uv[p][jj]*SEL[p][jj]) }

        PROJ_PASS(uz, dga_z)
        PROJ_PASS(ug, dga_g)
        PROJ_PASS(ur, dga_r)
        PROJ_PASS(uh, dga_h)
        PROJ_PASS(w1, v0)

        // reduce over jg: scratch rows 24..55 of Db (plain layout, disjoint from V rows)
        *(float4*)(Db + (24 + jg)*32 + p0) = make_float4(proj[0], proj[1], proj[2], proj[3]);
        __syncthreads();
        if (t < TM){
            float s = 0.f;
            for (int j2 = 0; j2 < 32; j2++) s += Db[(24 + j2)*32 + t];
            atomicAdd(t12acc + base_n + t, s);
        }
    } else {
        // type 0: full fprime
        float dxp[3] = {0.f, 0.f, 0.f};
        int pi = t >> 3, il = t & 7;

#define DX_PASS(UMAT, SEL) \
        __syncthreads(); \
        write_own(Db, SEL, j0, p0); \
        __syncthreads(); \
        _Pragma("unroll") for (int ii = 0; ii < 3; ii++){ \
            int i = il + 8*ii; \
            if (i < DD){ \
                const float* Urow = UMAT + i*UNITS; \
                float a = 0.f; \
                for (int j2 = 0; j2 < UNITS; j2++) a = fmaf(Db[offs(j2, pi)], Urow[j2], a); \
                dxp[ii] += a; \
            } \
        }

        DX_PASS(uz, dga_z)
        DX_PASS(ug, dga_g)
        DX_PASS(ur, dga_r)
        DX_PASS(uh, dga_h)
        DX_PASS(w1, v0)

        #pragma unroll
        for (int ii = 0; ii < 3; ii++){
            int i = il + 8*ii;
            if (i < DD) fp1[(P0 + pi)*DD + i] = dxp[ii];
        }
    }
}

__global__ void finalize_k(const float* __restrict__ inputs, const float* __restrict__ eps,
    const float* __restrict__ Lm, const float* __restrict__ fp1, const float* __restrict__ val1,
    const float* __restrict__ val2, const float* __restrict__ t12acc, float* __restrict__ out)
{
    int n = blockIdx.x*256 + threadIdx.x;
    if (n >= NN) return;
    float fp[DD];
    #pragma unroll
    for (int k = 0; k < DD; k++) fp[k] = fp1[n*DD + k];
    float t11 = fp[DIMN];
    #pragma unroll
    for (int k = 0; k < DIMN; k++) t11 = fmaf(MUC*inputs[n*DD + k], fp[k], t11);
    float esum[DIMN];
    #pragma unroll
    for (int d = 0; d < DIMN; d++){
        float a = 0.f;
        for (int m = 0; m < MCN; m++) a += eps[(size_t)(m*NN + n)*DIMN + d];
        esum[d] = a;
    }
    float t12b = 0.f;
    #pragma unroll
    for (int k = 0; k < DIMN; k++){
        float loc = inputs[n*DD + k];
        float ssum = (float)MCN * loc;
        #pragma unroll
        for (int d = 0; d < DIMN; d++) ssum = fmaf(esum[d], Lm[k*DIMN + d], ssum);
        float vsum = ssum * (SIGC*loc);
        t12b = fmaf(fp[k], vsum, t12b);
    }
    float term12 = (t12acc[n] - t12b) * (1.0f/(DELTAC*(float)MCN));
    out[n] = t11 + 0.5f*term12 - RC*val1[n];

    float prod = 1.f;
    #pragma unroll
    for (int k = 0; k < DIMN; k++) prod *= inputs[(NN + n)*DD + k];
    float payoff = powf(prod, 1.0f/(float)DIMN);
    if (!(payoff > 0.f)) payoff = 0.f;
    out[NN + n] = val2[n] - payoff;
}

extern "C" void kernel_launch(void* const* d_in, const int* in_sizes, int n_in,
                              void* d_out, int out_size, void* d_ws, size_t ws_size,
                              hipStream_t stream)
{
    const float* inputs = (const float*)d_in[0];
    const float* eps    = (const float*)d_in[1];
    const float* w1     = (const float*)d_in[2];
    const float* b1     = (const float*)d_in[3];
    const float* uz     = (const float*)d_in[4];
    const float* wz     = (const float*)d_in[5];
    const float* bz     = (const float*)d_in[6];
    const float* ug     = (const float*)d_in[7];
    const float* wg     = (const float*)d_in[8];
    const float* bg     = (const float*)d_in[9];
    const float* urr    = (const float*)d_in[10];
    const float* wr     = (const float*)d_in[11];
    const float* br     = (const float*)d_in[12];
    const float* uh     = (const float*)d_in[13];
    const float* wh     = (const float*)d_in[14];
    const float* bh     = (const float*)d_in[15];
    const float* wv     = (const float*)d_in[16];
    const float* bv     = (const float*)d_in[17];

    float* ws   = (float*)d_ws;
    float* Lm   = ws + OFF_L;
    float* WT   = ws + OFF_WT;
    float* fp1  = ws + OFF_FP1;
    float* val1 = ws + OFF_VAL1;
    float* val2 = ws + OFF_VAL2;
    float* t12  = ws + OFF_T12;
    float* out  = (float*)d_out;

    hipMemsetAsync(t12, 0, NN*sizeof(float), stream);
    hipLaunchKernelGGL(chol_kernel, dim3(1), dim3(64), 0, stream, Lm);
    hipLaunchKernelGGL(transpose_k, dim3(256), dim3(256), 0, stream, wz, wg, wr, wh, WT);
    hipLaunchKernelGGL(dgm_main, dim3(NBLK), dim3(256), 0, stream,
        inputs, eps, w1, b1, uz, wz, bz, ug, wg, bg, urr, wr, br, uh, wh, bh, wv, bv,
        Lm, WT, fp1, val1, val2, t12);
    hipLaunchKernelGGL(finalize_k, dim3(8), dim3(256), 0, stream,
        inputs, eps, Lm, fp1, val1, val2, t12, out);
}